// Round 2
// baseline (320.101 us; speedup 1.0000x reference)
//
#include <hip/hip_runtime.h>

#define BATCH 8
#define DIMC 128
#define NTOT 32768
#define HEADS 4
#define DHEAD 32
#define SCALE_Q 0.17677669529663687f

typedef _Float16 half8  __attribute__((ext_vector_type(8)));
typedef _Float16 half4v __attribute__((ext_vector_type(4)));
typedef _Float16 half2v __attribute__((ext_vector_type(2)));
typedef float    f32x4  __attribute__((ext_vector_type(4)));

// workspace byte offsets (all 16B aligned)
#define WS_WQKV 0        // _Float16[384*128]   = 98304 B
#define WS_WOUT 98304    // _Float16[128*128]   = 32768 B
#define WS_S    131072   // float[8*4*32*32]    = 131072 B
#define WS_Z    262144   // float[8*4*32]       = 4096 B
#define WS_C    266240   // float[8*4*32*32]    = 131072 B
#define WS_ST   397312   // float[16]
#define WS_NEED 397376

// XOR swizzle: column c of row `row`, 8-element granularity
#define SWZ(row, c) ((c) ^ ((((row) >> 2) & 7) << 3))

// ---------------- K0: convert weights to f16, zero accumulators ----------------
__global__ void k0_prep(const float* __restrict__ wqkv, const float* __restrict__ wout,
                        char* __restrict__ ws) {
    int i = blockIdx.x * 256 + threadIdx.x;
    _Float16* Wb = (_Float16*)(ws + WS_WQKV);
    _Float16* Wo = (_Float16*)(ws + WS_WOUT);
    float* S  = (float*)(ws + WS_S);
    float* Z  = (float*)(ws + WS_Z);
    float* St = (float*)(ws + WS_ST);
    if (i < 49152) Wb[i] = (_Float16)wqkv[i];
    int j = i - 49152;
    if (j >= 0 && j < 16384) Wo[j] = (_Float16)wout[j];
    int k = j - 16384;
    if (k >= 0 && k < 32768) S[k] = 0.f;
    int m = k - 32768;
    if (m >= 0 && m < 1024) Z[m] = 0.f;
    int s = m - 1024;
    if (s >= 0 && s < 16) St[s] = 0.f;
}

// ---------------- K1: k,v projection + S = sum_n exp(k) v^T, Z = sum_n exp(k) ----------------
__global__ __launch_bounds__(256, 3) void k1_kv(const float* __restrict__ x,
                                                const _Float16* __restrict__ Wb,
                                                float* __restrict__ S,
                                                float* __restrict__ Z) {
    __shared__ _Float16 Xb[64][136];   // x^T tile: [j][c swizzled]
    __shared__ _Float16 KB[128][72];   // exp(k): [h*32+d][j swizzled]
    __shared__ _Float16 VB[128][72];   // v:      [h*32+e][j swizzled]
    const int t = threadIdx.x;
    const int lane = t & 63, w = t >> 6, g = lane >> 4, l15 = lane & 15;
    const int b = blockIdx.y;

    half8 af[4][4];
#pragma unroll
    for (int mt = 0; mt < 4; ++mt)
#pragma unroll
        for (int kc = 0; kc < 4; ++kc)
            af[mt][kc] = *(const half8*)(Wb + (size_t)(128 + (w * 4 + mt) * 16 + l15) * 128 + kc * 32 + 8 * g);

    f32x4 sacc[2][2];
#pragma unroll
    for (int dm = 0; dm < 2; ++dm)
#pragma unroll
        for (int en = 0; en < 2; ++en) sacc[dm][en] = (f32x4){0.f, 0.f, 0.f, 0.f};
    float zpart = 0.f;

    const int j4 = t & 15, c0 = t >> 4;
    const int sxw = (j4 & 7) << 3;  // staging swizzle for rows 4*j4+r (r<4)

    for (int it = 0; it < 8; ++it) {
        const int j0 = (blockIdx.x + 64 * it) * 64;
        __syncthreads();
#pragma unroll
        for (int cc = 0; cc < 8; ++cc) {
            const int c = c0 + 16 * cc;
            const float4 v4 = *(const float4*)(x + ((size_t)b * DIMC + c) * NTOT + j0 + 4 * j4);
            Xb[4 * j4 + 0][c ^ sxw] = (_Float16)v4.x;
            Xb[4 * j4 + 1][c ^ sxw] = (_Float16)v4.y;
            Xb[4 * j4 + 2][c ^ sxw] = (_Float16)v4.z;
            Xb[4 * j4 + 3][c ^ sxw] = (_Float16)v4.w;
        }
        __syncthreads();
        half8 bf[4][4];
#pragma unroll
        for (int nt = 0; nt < 4; ++nt) {
            const int sb = ((4 * nt + (l15 >> 2)) & 7) << 3;
#pragma unroll
            for (int kc = 0; kc < 4; ++kc)
                bf[nt][kc] = *(const half8*)(&Xb[nt * 16 + l15][(kc * 32 + 8 * g) ^ sb]);
        }
#pragma unroll
        for (int mt = 0; mt < 4; ++mt) {
            f32x4 a0 = (f32x4){0.f,0.f,0.f,0.f}, a1 = a0, a2 = a0, a3 = a0;
#pragma unroll
            for (int kc = 0; kc < 4; ++kc) {
                a0 = __builtin_amdgcn_mfma_f32_16x16x32_f16(af[mt][kc], bf[0][kc], a0, 0, 0, 0);
                a1 = __builtin_amdgcn_mfma_f32_16x16x32_f16(af[mt][kc], bf[1][kc], a1, 0, 0, 0);
                a2 = __builtin_amdgcn_mfma_f32_16x16x32_f16(af[mt][kc], bf[2][kc], a2, 0, 0, 0);
                a3 = __builtin_amdgcn_mfma_f32_16x16x32_f16(af[mt][kc], bf[3][kc], a3, 0, 0, 0);
            }
            const int lr0 = (w * 4 + mt) * 16 + g * 4;
            const int skv = (((w * 4 + mt) * 4 + g) & 7) << 3;  // ((lr0+r)>>2)&7, r<4
#pragma unroll
            for (int nt = 0; nt < 4; ++nt) {
                const f32x4 a = (nt == 0) ? a0 : (nt == 1) ? a1 : (nt == 2) ? a2 : a3;
                const int jn = (nt * 16 + l15) ^ skv;
                if (lr0 < 128) {
#pragma unroll
                    for (int r = 0; r < 4; ++r) KB[lr0 + r][jn] = (_Float16)__expf(a[r]);
                } else {
#pragma unroll
                    for (int r = 0; r < 4; ++r) VB[lr0 - 128 + r][jn] = (_Float16)a[r];
                }
            }
        }
        __syncthreads();
#pragma unroll
        for (int dm = 0; dm < 2; ++dm) {
            const int sr = ((4 * dm + (l15 >> 2)) & 7) << 3;
#pragma unroll
            for (int en = 0; en < 2; ++en)
#pragma unroll
                for (int kc = 0; kc < 2; ++kc) {
                    half8 ka = *(const half8*)(&KB[w * 32 + dm * 16 + l15][(kc * 32 + 8 * g) ^ sr]);
                    half8 vb = *(const half8*)(&VB[w * 32 + en * 16 + l15][(kc * 32 + 8 * g) ^ sr]);
                    sacc[dm][en] = __builtin_amdgcn_mfma_f32_16x16x32_f16(ka, vb, sacc[dm][en], 0, 0, 0);
                }
        }
        {
            const int zr = lane >> 1;
            const int sz = ((zr >> 2) & 7) << 3;
#pragma unroll
            for (int s8 = 0; s8 < 4; ++s8) {
                half8 hv = *(const half8*)(&KB[w * 32 + zr][((lane & 1) * 32 + 8 * s8) ^ sz]);
#pragma unroll
                for (int e = 0; e < 8; ++e) zpart += (float)hv[e];
            }
        }
    }
    {
        float zt = zpart + __shfl_xor(zpart, 1);
        if ((lane & 1) == 0) atomicAdd(&Z[(b * HEADS + w) * DHEAD + (lane >> 1)], zt);
    }
#pragma unroll
    for (int dm = 0; dm < 2; ++dm)
#pragma unroll
        for (int en = 0; en < 2; ++en)
#pragma unroll
            for (int r = 0; r < 4; ++r)
                atomicAdd(&S[((size_t)(b * HEADS + w) * DHEAD + dm * 16 + g * 4 + r) * DHEAD + en * 16 + l15],
                          sacc[dm][en][r]);
}

// ---------------- K2: c = S / Z ----------------
__global__ void k2_c(const float* __restrict__ S, const float* __restrict__ Z,
                     float* __restrict__ C) {
    int i = blockIdx.x * 256 + threadIdx.x;
    C[i] = S[i] / Z[i >> 5];
}

// ---------------- K3: q proj + d-softmax + out = c^T q + y (f16 stash) + stats ----------------
__global__ __launch_bounds__(256, 4) void k3_main(const float* __restrict__ x,
                                                  const _Float16* __restrict__ Wb,
                                                  const _Float16* __restrict__ Wo,
                                                  const float* __restrict__ Cb,
                                                  const float* __restrict__ b_out,
                                                  char* __restrict__ ybase,
                                                  float* __restrict__ St) {
    __shared__ _Float16 Xb[64][136];  // phase 1-2: x^T; phase 3-4: reused as oT
    __shared__ _Float16 qT[64][136];
    __shared__ float red[8];
    const int t = threadIdx.x;
    const int lane = t & 63, w = t >> 6, g = lane >> 4, l15 = lane & 15;
    const int b = blockIdx.y;
    const int j0 = blockIdx.x * 64;

    // phase 1: stage x^T tile (swizzled)
    {
        const int j4 = t & 15, c0 = t >> 4;
        const int sxw = (j4 & 7) << 3;
#pragma unroll
        for (int cc = 0; cc < 8; ++cc) {
            const int c = c0 + 16 * cc;
            const float4 v4 = *(const float4*)(x + ((size_t)b * DIMC + c) * NTOT + j0 + 4 * j4);
            Xb[4 * j4 + 0][c ^ sxw] = (_Float16)v4.x;
            Xb[4 * j4 + 1][c ^ sxw] = (_Float16)v4.y;
            Xb[4 * j4 + 2][c ^ sxw] = (_Float16)v4.z;
            Xb[4 * j4 + 3][c ^ sxw] = (_Float16)v4.w;
        }
    }
    __syncthreads();
    // phase 2: q GEMM (rows 0..127), write q^T to LDS
    {
        half8 bf[4][4];
#pragma unroll
        for (int nt = 0; nt < 4; ++nt) {
            const int sb = ((4 * nt + (l15 >> 2)) & 7) << 3;
#pragma unroll
            for (int kc = 0; kc < 4; ++kc)
                bf[nt][kc] = *(const half8*)(&Xb[nt * 16 + l15][(kc * 32 + 8 * g) ^ sb]);
        }
#pragma unroll
        for (int mi = 0; mi < 2; ++mi) {
            const int mt = w * 2 + mi;
            half8 af[4];
#pragma unroll
            for (int kc = 0; kc < 4; ++kc)
                af[kc] = *(const half8*)(Wb + (size_t)(mt * 16 + l15) * 128 + kc * 32 + 8 * g);
            f32x4 acc[4];
#pragma unroll
            for (int nt = 0; nt < 4; ++nt) acc[nt] = (f32x4){0.f, 0.f, 0.f, 0.f};
#pragma unroll
            for (int kc = 0; kc < 4; ++kc)
#pragma unroll
                for (int nt = 0; nt < 4; ++nt)
                    acc[nt] = __builtin_amdgcn_mfma_f32_16x16x32_f16(af[kc], bf[nt][kc], acc[nt], 0, 0, 0);
#pragma unroll
            for (int nt = 0; nt < 4; ++nt) {
                const int sb = ((4 * nt + (l15 >> 2)) & 7) << 3;
                half4v p;
#pragma unroll
                for (int r = 0; r < 4; ++r) p[r] = (_Float16)acc[nt][r];
                *(half4v*)(&qT[nt * 16 + l15][(mt * 16 + g * 4) ^ sb]) = p;
            }
        }
    }
    __syncthreads();
    // phase 3: per-column d-softmax + out = c^T q  -> write oT (aliases Xb)
    {
        const int j = t & 63;
        const int h = __builtin_amdgcn_readfirstlane(t >> 6);
        const int sj = ((j >> 2) & 7) << 3;
        float qv[32];
#pragma unroll
        for (int s8 = 0; s8 < 4; ++s8) {
            half8 hv = *(const half8*)(&qT[j][(h * 32 + 8 * s8) ^ sj]);
#pragma unroll
            for (int e = 0; e < 8; ++e) qv[8 * s8 + e] = (float)hv[e];
        }
        float se = 0.f;
#pragma unroll
        for (int d = 0; d < 32; ++d) { qv[d] = __expf(qv[d]); se += qv[d]; }
        const float inv = SCALE_Q / se;
        float outv[32];
#pragma unroll
        for (int e = 0; e < 32; ++e) outv[e] = 0.f;
        const float* ch = Cb + (size_t)(b * HEADS + h) * DHEAD * DHEAD;
#pragma unroll
        for (int d = 0; d < 32; ++d) {
            const float qd = qv[d] * inv;
#pragma unroll
            for (int e = 0; e < 32; ++e) outv[e] = fmaf(ch[d * 32 + e], qd, outv[e]);
        }
        __syncthreads();  // ensure phase-2 Xb reads done before overwrite
#pragma unroll
        for (int e = 0; e < 32; e += 2) {
            half2v p = {(_Float16)outv[e], (_Float16)outv[e + 1]};
            *(half2v*)(&Xb[j][(h * 32 + e) ^ sj]) = p;
        }
    }
    __syncthreads();
    // phase 4: y = Wout @ out + b_out -> f16 stash in d_out rows, + stats
    float ssum = 0.f, ssq = 0.f;
    {
        half8 bf[4][4];
#pragma unroll
        for (int nt = 0; nt < 4; ++nt) {
            const int sb = ((4 * nt + (l15 >> 2)) & 7) << 3;
#pragma unroll
            for (int kc = 0; kc < 4; ++kc)
                bf[nt][kc] = *(const half8*)(&Xb[nt * 16 + l15][(kc * 32 + 8 * g) ^ sb]);
        }
#pragma unroll
        for (int mi = 0; mi < 2; ++mi) {
            const int mt = w * 2 + mi;
            const int o0 = mt * 16 + g * 4;
            half8 af[4];
#pragma unroll
            for (int kc = 0; kc < 4; ++kc)
                af[kc] = *(const half8*)(Wo + (size_t)(mt * 16 + l15) * 128 + kc * 32 + 8 * g);
            f32x4 acc[4];
#pragma unroll
            for (int nt = 0; nt < 4; ++nt) acc[nt] = (f32x4){0.f, 0.f, 0.f, 0.f};
#pragma unroll
            for (int kc = 0; kc < 4; ++kc)
#pragma unroll
                for (int nt = 0; nt < 4; ++nt)
                    acc[nt] = __builtin_amdgcn_mfma_f32_16x16x32_f16(af[kc], bf[nt][kc], acc[nt], 0, 0, 0);
            float bo[4];
#pragma unroll
            for (int r = 0; r < 4; ++r) bo[r] = b_out[o0 + r];
#pragma unroll
            for (int r = 0; r < 4; ++r) {
                _Float16* yrow = (_Float16*)(ybase + (size_t)(b * DIMC + o0 + r) * 131072 + 65536);
#pragma unroll
                for (int nt = 0; nt < 4; ++nt) {
                    const int jn = j0 + nt * 16 + l15;
                    const float yv = acc[nt][r] + bo[r];
                    ssum += yv;
                    ssq += yv * yv;
                    yrow[jn] = (_Float16)yv;
                }
            }
        }
    }
#pragma unroll
    for (int m = 32; m; m >>= 1) { ssum += __shfl_xor(ssum, m); ssq += __shfl_xor(ssq, m); }
    if (lane == 0) { red[w] = ssum; red[4 + w] = ssq; }
    __syncthreads();
    if (t == 0) {
        atomicAdd(&St[b * 2 + 0], red[0] + red[1] + red[2] + red[3]);
        atomicAdd(&St[b * 2 + 1], red[4] + red[5] + red[6] + red[7]);
    }
}

// ---------------- K4: layernorm; read f16 stash (2nd half of own row), write f32 ----------------
__global__ __launch_bounds__(256) void k4_norm(float* __restrict__ out, const float* __restrict__ St,
                                               const float* __restrict__ gamma,
                                               const float* __restrict__ beta) {
    const int o = blockIdx.x;
    const int b = blockIdx.y;
    const int t = threadIdx.x;
    const size_t row = (size_t)b * DIMC + o;
    const float n = (float)DIMC * (float)NTOT;
    const float mean = St[b * 2] / n;
    const float var = St[b * 2 + 1] / n - mean * mean;
    const float rs = rsqrtf(var + 1e-5f);
    const float ga = gamma[o] * rs;
    const float be = beta[o];
    const half8* yh = (const half8*)((const char*)out + row * 131072 + 65536);
    half8 hbuf[16];
#pragma unroll
    for (int i = 0; i < 16; ++i) hbuf[i] = yh[i * 256 + t];
    __syncthreads();  // all reads before any f32 overwrite (stash lives in this row)
    float4* orow = (float4*)(out + row * NTOT);
#pragma unroll
    for (int i = 0; i < 16; ++i) {
        const int e4 = (i * 256 + t) * 2;
        float4 v0, v1;
        v0.x = ((float)hbuf[i][0] - mean) * ga + be;
        v0.y = ((float)hbuf[i][1] - mean) * ga + be;
        v0.z = ((float)hbuf[i][2] - mean) * ga + be;
        v0.w = ((float)hbuf[i][3] - mean) * ga + be;
        v1.x = ((float)hbuf[i][4] - mean) * ga + be;
        v1.y = ((float)hbuf[i][5] - mean) * ga + be;
        v1.z = ((float)hbuf[i][6] - mean) * ga + be;
        v1.w = ((float)hbuf[i][7] - mean) * ga + be;
        orow[e4] = v0;
        orow[e4 + 1] = v1;
    }
}

extern "C" void kernel_launch(void* const* d_in, const int* in_sizes, int n_in,
                              void* d_out, int out_size, void* d_ws, size_t ws_size,
                              hipStream_t stream) {
    const float* x     = (const float*)d_in[0];
    const float* wqkv  = (const float*)d_in[1];
    const float* wout  = (const float*)d_in[2];
    const float* b_out = (const float*)d_in[3];
    const float* gamma = (const float*)d_in[4];
    const float* beta  = (const float*)d_in[5];
    if (ws_size < WS_NEED) return;
    char* ws = (char*)d_ws;
    _Float16* Wb = (_Float16*)(ws + WS_WQKV);
    _Float16* Wo = (_Float16*)(ws + WS_WOUT);
    float* S  = (float*)(ws + WS_S);
    float* Z  = (float*)(ws + WS_Z);
    float* Cb = (float*)(ws + WS_C);
    float* St = (float*)(ws + WS_ST);

    k0_prep<<<389, 256, 0, stream>>>(wqkv, wout, ws);
    k1_kv<<<dim3(64, 8), 256, 0, stream>>>(x, Wb, S, Z);
    k2_c<<<128, 256, 0, stream>>>(S, Z, Cb);
    k3_main<<<dim3(512, 8), 256, 0, stream>>>(x, Wb, Wo, Cb, b_out, (char*)d_out, St);
    k4_norm<<<dim3(128, 8), 256, 0, stream>>>((float*)d_out, St, gamma, beta);
}

// Round 3
// 230.344 us; speedup vs baseline: 1.3897x; 1.3897x over previous
//
#include <hip/hip_runtime.h>

#define BATCH 8
#define DIMC 128
#define NTOT 32768
#define HEADS 4
#define DHEAD 32
#define SCALE_Q 0.17677669529663687f

typedef _Float16 half8  __attribute__((ext_vector_type(8)));
typedef _Float16 half4v __attribute__((ext_vector_type(4)));
typedef _Float16 half2v __attribute__((ext_vector_type(2)));
typedef float    f32x4  __attribute__((ext_vector_type(4)));

// workspace byte offsets (all 16B aligned)
#define WS_WQKV 0        // _Float16[384*128]   = 98304 B
#define WS_WOUT 98304    // _Float16[128*128]   = 32768 B
#define WS_S    131072   // float[8*4*32*32]    = 131072 B
#define WS_Z    262144   // float[8*4*32]       = 4096 B
#define WS_ST   266240   // float[16]
#define WS_NEED 266304

// ---------------- K0: convert weights to f16, zero accumulators ----------------
__global__ void k0_prep(const float* __restrict__ wqkv, const float* __restrict__ wout,
                        char* __restrict__ ws) {
    int i = blockIdx.x * 256 + threadIdx.x;
    _Float16* Wb = (_Float16*)(ws + WS_WQKV);
    _Float16* Wo = (_Float16*)(ws + WS_WOUT);
    float* S  = (float*)(ws + WS_S);
    float* Z  = (float*)(ws + WS_Z);
    float* St = (float*)(ws + WS_ST);
    if (i < 49152) Wb[i] = (_Float16)wqkv[i];
    int j = i - 49152;
    if (j >= 0 && j < 16384) Wo[j] = (_Float16)wout[j];
    int k = j - 16384;
    if (k >= 0 && k < 32768) S[k] = 0.f;
    int m = k - 32768;
    if (m >= 0 && m < 1024) Z[m] = 0.f;
    int s = m - 1024;
    if (s >= 0 && s < 16) St[s] = 0.f;
}

// ---------------- K1: k,v projection + S = sum_n exp(k) v^T, Z = sum_n exp(k) ----------------
// (256,2): LDS (54.3 KB) caps at 2 blocks/CU anyway; (256,3) forced VGPR=84 + scratch
// spills (102 MB writes, +65 MB fetch) and tripled duration. Keep register budget loose.
__global__ __launch_bounds__(256, 2) void k1_kv(const float* __restrict__ x,
                                                const _Float16* __restrict__ Wb,
                                                float* __restrict__ S,
                                                float* __restrict__ Z) {
    __shared__ _Float16 Xb[64][136];   // x^T tile: [j][c swizzled]
    __shared__ _Float16 KB[128][72];   // exp(k): [h*32+d][j swizzled]
    __shared__ _Float16 VB[128][72];   // v:      [h*32+e][j swizzled]
    const int t = threadIdx.x;
    const int lane = t & 63, w = t >> 6, g = lane >> 4, l15 = lane & 15;
    const int b = blockIdx.y;

    half8 af[4][4];
#pragma unroll
    for (int mt = 0; mt < 4; ++mt)
#pragma unroll
        for (int kc = 0; kc < 4; ++kc)
            af[mt][kc] = *(const half8*)(Wb + (size_t)(128 + (w * 4 + mt) * 16 + l15) * 128 + kc * 32 + 8 * g);

    f32x4 sacc[2][2];
#pragma unroll
    for (int dm = 0; dm < 2; ++dm)
#pragma unroll
        for (int en = 0; en < 2; ++en) sacc[dm][en] = (f32x4){0.f, 0.f, 0.f, 0.f};
    float zpart = 0.f;

    const int j4 = t & 15, c0 = t >> 4;
    const int sxw = (j4 & 7) << 3;  // staging swizzle for rows 4*j4+r (r<4)

    for (int it = 0; it < 8; ++it) {
        const int j0 = (blockIdx.x + 64 * it) * 64;
        __syncthreads();
#pragma unroll
        for (int cc = 0; cc < 8; ++cc) {
            const int c = c0 + 16 * cc;
            const float4 v4 = *(const float4*)(x + ((size_t)b * DIMC + c) * NTOT + j0 + 4 * j4);
            Xb[4 * j4 + 0][c ^ sxw] = (_Float16)v4.x;
            Xb[4 * j4 + 1][c ^ sxw] = (_Float16)v4.y;
            Xb[4 * j4 + 2][c ^ sxw] = (_Float16)v4.z;
            Xb[4 * j4 + 3][c ^ sxw] = (_Float16)v4.w;
        }
        __syncthreads();
        half8 bf[4][4];
#pragma unroll
        for (int nt = 0; nt < 4; ++nt) {
            const int sb = ((4 * nt + (l15 >> 2)) & 7) << 3;
#pragma unroll
            for (int kc = 0; kc < 4; ++kc)
                bf[nt][kc] = *(const half8*)(&Xb[nt * 16 + l15][(kc * 32 + 8 * g) ^ sb]);
        }
#pragma unroll
        for (int mt = 0; mt < 4; ++mt) {
            f32x4 a0 = (f32x4){0.f,0.f,0.f,0.f}, a1 = a0, a2 = a0, a3 = a0;
#pragma unroll
            for (int kc = 0; kc < 4; ++kc) {
                a0 = __builtin_amdgcn_mfma_f32_16x16x32_f16(af[mt][kc], bf[0][kc], a0, 0, 0, 0);
                a1 = __builtin_amdgcn_mfma_f32_16x16x32_f16(af[mt][kc], bf[1][kc], a1, 0, 0, 0);
                a2 = __builtin_amdgcn_mfma_f32_16x16x32_f16(af[mt][kc], bf[2][kc], a2, 0, 0, 0);
                a3 = __builtin_amdgcn_mfma_f32_16x16x32_f16(af[mt][kc], bf[3][kc], a3, 0, 0, 0);
            }
            const int lr0 = (w * 4 + mt) * 16 + g * 4;
            const int skv = (((w * 4 + mt) * 4 + g) & 7) << 3;  // ((lr0+r)>>2)&7, r<4
#pragma unroll
            for (int nt = 0; nt < 4; ++nt) {
                const f32x4 a = (nt == 0) ? a0 : (nt == 1) ? a1 : (nt == 2) ? a2 : a3;
                const int jn = (nt * 16 + l15) ^ skv;
                if (lr0 < 128) {
#pragma unroll
                    for (int r = 0; r < 4; ++r) KB[lr0 + r][jn] = (_Float16)__expf(a[r]);
                } else {
#pragma unroll
                    for (int r = 0; r < 4; ++r) VB[lr0 - 128 + r][jn] = (_Float16)a[r];
                }
            }
        }
        __syncthreads();
#pragma unroll
        for (int dm = 0; dm < 2; ++dm) {
            const int sr = ((4 * dm + (l15 >> 2)) & 7) << 3;
#pragma unroll
            for (int en = 0; en < 2; ++en)
#pragma unroll
                for (int kc = 0; kc < 2; ++kc) {
                    half8 ka = *(const half8*)(&KB[w * 32 + dm * 16 + l15][(kc * 32 + 8 * g) ^ sr]);
                    half8 vb = *(const half8*)(&VB[w * 32 + en * 16 + l15][(kc * 32 + 8 * g) ^ sr]);
                    sacc[dm][en] = __builtin_amdgcn_mfma_f32_16x16x32_f16(ka, vb, sacc[dm][en], 0, 0, 0);
                }
        }
        {
            const int zr = lane >> 1;
            const int sz = ((zr >> 2) & 7) << 3;
#pragma unroll
            for (int s8 = 0; s8 < 4; ++s8) {
                half8 hv = *(const half8*)(&KB[w * 32 + zr][((lane & 1) * 32 + 8 * s8) ^ sz]);
#pragma unroll
                for (int e = 0; e < 8; ++e) zpart += (float)hv[e];
            }
        }
    }
    {
        float zt = zpart + __shfl_xor(zpart, 1);
        if ((lane & 1) == 0) atomicAdd(&Z[(b * HEADS + w) * DHEAD + (lane >> 1)], zt);
    }
#pragma unroll
    for (int dm = 0; dm < 2; ++dm)
#pragma unroll
        for (int en = 0; en < 2; ++en)
#pragma unroll
            for (int r = 0; r < 4; ++r)
                atomicAdd(&S[((size_t)(b * HEADS + w) * DHEAD + dm * 16 + g * 4 + r) * DHEAD + en * 16 + l15],
                          sacc[dm][en][r]);
}

// ---------------- K3: q proj + d-softmax + out = (S/Z)^T q + y (f16 stash) + stats ----------------
__global__ __launch_bounds__(256, 2) void k3_main(const float* __restrict__ x,
                                                  const _Float16* __restrict__ Wb,
                                                  const _Float16* __restrict__ Wo,
                                                  const float* __restrict__ Sb,
                                                  const float* __restrict__ Zb,
                                                  const float* __restrict__ b_out,
                                                  char* __restrict__ ybase,
                                                  float* __restrict__ St) {
    __shared__ _Float16 Xb[64][136];  // phase 1-2: x^T; phase 3-4: reused as oT
    __shared__ _Float16 qT[64][136];
    __shared__ float red[8];
    const int t = threadIdx.x;
    const int lane = t & 63, w = t >> 6, g = lane >> 4, l15 = lane & 15;
    const int b = blockIdx.y;
    const int j0 = blockIdx.x * 64;

    // phase 1: stage x^T tile (swizzled)
    {
        const int j4 = t & 15, c0 = t >> 4;
        const int sxw = (j4 & 7) << 3;
#pragma unroll
        for (int cc = 0; cc < 8; ++cc) {
            const int c = c0 + 16 * cc;
            const float4 v4 = *(const float4*)(x + ((size_t)b * DIMC + c) * NTOT + j0 + 4 * j4);
            Xb[4 * j4 + 0][c ^ sxw] = (_Float16)v4.x;
            Xb[4 * j4 + 1][c ^ sxw] = (_Float16)v4.y;
            Xb[4 * j4 + 2][c ^ sxw] = (_Float16)v4.z;
            Xb[4 * j4 + 3][c ^ sxw] = (_Float16)v4.w;
        }
    }
    __syncthreads();
    // phase 2: q GEMM (rows 0..127), write q^T to LDS
    {
        half8 bf[4][4];
#pragma unroll
        for (int nt = 0; nt < 4; ++nt) {
            const int sb = ((4 * nt + (l15 >> 2)) & 7) << 3;
#pragma unroll
            for (int kc = 0; kc < 4; ++kc)
                bf[nt][kc] = *(const half8*)(&Xb[nt * 16 + l15][(kc * 32 + 8 * g) ^ sb]);
        }
#pragma unroll
        for (int mi = 0; mi < 2; ++mi) {
            const int mt = w * 2 + mi;
            half8 af[4];
#pragma unroll
            for (int kc = 0; kc < 4; ++kc)
                af[kc] = *(const half8*)(Wb + (size_t)(mt * 16 + l15) * 128 + kc * 32 + 8 * g);
            f32x4 acc[4];
#pragma unroll
            for (int nt = 0; nt < 4; ++nt) acc[nt] = (f32x4){0.f, 0.f, 0.f, 0.f};
#pragma unroll
            for (int kc = 0; kc < 4; ++kc)
#pragma unroll
                for (int nt = 0; nt < 4; ++nt)
                    acc[nt] = __builtin_amdgcn_mfma_f32_16x16x32_f16(af[kc], bf[nt][kc], acc[nt], 0, 0, 0);
#pragma unroll
            for (int nt = 0; nt < 4; ++nt) {
                const int sb = ((4 * nt + (l15 >> 2)) & 7) << 3;
                half4v p;
#pragma unroll
                for (int r = 0; r < 4; ++r) p[r] = (_Float16)acc[nt][r];
                *(half4v*)(&qT[nt * 16 + l15][(mt * 16 + g * 4) ^ sb]) = p;
            }
        }
    }
    __syncthreads();
    // phase 3: per-column d-softmax + out = (S/Z)^T q  -> write oT (aliases Xb)
    {
        const int j = t & 63;
        const int h = __builtin_amdgcn_readfirstlane(t >> 6);
        const int sj = ((j >> 2) & 7) << 3;
        float qv[32];
#pragma unroll
        for (int s8 = 0; s8 < 4; ++s8) {
            half8 hv = *(const half8*)(&qT[j][(h * 32 + 8 * s8) ^ sj]);
#pragma unroll
            for (int e = 0; e < 8; ++e) qv[8 * s8 + e] = (float)hv[e];
        }
        float se = 0.f;
#pragma unroll
        for (int d = 0; d < 32; ++d) { qv[d] = __expf(qv[d]); se += qv[d]; }
        const float inv = SCALE_Q / se;
        float outv[32];
#pragma unroll
        for (int e = 0; e < 32; ++e) outv[e] = 0.f;
        const float* sh = Sb + (size_t)(b * HEADS + h) * DHEAD * DHEAD;
        const float* zh = Zb + (size_t)(b * HEADS + h) * DHEAD;
#pragma unroll
        for (int d = 0; d < 32; ++d) {
            const float qd = qv[d] * inv / zh[d];
#pragma unroll
            for (int e = 0; e < 32; ++e) outv[e] = fmaf(sh[d * 32 + e], qd, outv[e]);
        }
        __syncthreads();  // ensure phase-2 Xb reads done before overwrite
#pragma unroll
        for (int e = 0; e < 32; e += 2) {
            half2v p = {(_Float16)outv[e], (_Float16)outv[e + 1]};
            *(half2v*)(&Xb[j][(h * 32 + e) ^ sj]) = p;
        }
    }
    __syncthreads();
    // phase 4: y = Wout @ out + b_out -> f16 stash in d_out rows, + stats
    float ssum = 0.f, ssq = 0.f;
    {
        half8 bf[4][4];
#pragma unroll
        for (int nt = 0; nt < 4; ++nt) {
            const int sb = ((4 * nt + (l15 >> 2)) & 7) << 3;
#pragma unroll
            for (int kc = 0; kc < 4; ++kc)
                bf[nt][kc] = *(const half8*)(&Xb[nt * 16 + l15][(kc * 32 + 8 * g) ^ sb]);
        }
#pragma unroll
        for (int mi = 0; mi < 2; ++mi) {
            const int mt = w * 2 + mi;
            const int o0 = mt * 16 + g * 4;
            half8 af[4];
#pragma unroll
            for (int kc = 0; kc < 4; ++kc)
                af[kc] = *(const half8*)(Wo + (size_t)(mt * 16 + l15) * 128 + kc * 32 + 8 * g);
            f32x4 acc[4];
#pragma unroll
            for (int nt = 0; nt < 4; ++nt) acc[nt] = (f32x4){0.f, 0.f, 0.f, 0.f};
#pragma unroll
            for (int kc = 0; kc < 4; ++kc)
#pragma unroll
                for (int nt = 0; nt < 4; ++nt)
                    acc[nt] = __builtin_amdgcn_mfma_f32_16x16x32_f16(af[kc], bf[nt][kc], acc[nt], 0, 0, 0);
            float bo[4];
#pragma unroll
            for (int r = 0; r < 4; ++r) bo[r] = b_out[o0 + r];
#pragma unroll
            for (int r = 0; r < 4; ++r) {
                _Float16* yrow = (_Float16*)(ybase + (size_t)(b * DIMC + o0 + r) * 131072 + 65536);
#pragma unroll
                for (int nt = 0; nt < 4; ++nt) {
                    const int jn = j0 + nt * 16 + l15;
                    const float yv = acc[nt][r] + bo[r];
                    ssum += yv;
                    ssq += yv * yv;
                    yrow[jn] = (_Float16)yv;
                }
            }
        }
    }
#pragma unroll
    for (int m = 32; m; m >>= 1) { ssum += __shfl_xor(ssum, m); ssq += __shfl_xor(ssq, m); }
    if (lane == 0) { red[w] = ssum; red[4 + w] = ssq; }
    __syncthreads();
    if (t == 0) {
        atomicAdd(&St[b * 2 + 0], red[0] + red[1] + red[2] + red[3]);
        atomicAdd(&St[b * 2 + 1], red[4] + red[5] + red[6] + red[7]);
    }
}

// ---------------- K4: layernorm; read f16 stash (2nd half of own row), write f32 ----------------
__global__ __launch_bounds__(256) void k4_norm(float* __restrict__ out, const float* __restrict__ St,
                                               const float* __restrict__ gamma,
                                               const float* __restrict__ beta) {
    const int o = blockIdx.x;
    const int b = blockIdx.y;
    const int t = threadIdx.x;
    const size_t row = (size_t)b * DIMC + o;
    const float n = (float)DIMC * (float)NTOT;
    const float mean = St[b * 2] / n;
    const float var = St[b * 2 + 1] / n - mean * mean;
    const float rs = rsqrtf(var + 1e-5f);
    const float ga = gamma[o] * rs;
    const float be = beta[o];
    const half8* yh = (const half8*)((const char*)out + row * 131072 + 65536);
    half8 hbuf[16];
#pragma unroll
    for (int i = 0; i < 16; ++i) hbuf[i] = yh[i * 256 + t];
    __syncthreads();  // all reads before any f32 overwrite (stash lives in this row)
    float4* orow = (float4*)(out + row * NTOT);
#pragma unroll
    for (int i = 0; i < 16; ++i) {
        const int e4 = (i * 256 + t) * 2;
        float4 v0, v1;
        v0.x = ((float)hbuf[i][0] - mean) * ga + be;
        v0.y = ((float)hbuf[i][1] - mean) * ga + be;
        v0.z = ((float)hbuf[i][2] - mean) * ga + be;
        v0.w = ((float)hbuf[i][3] - mean) * ga + be;
        v1.x = ((float)hbuf[i][4] - mean) * ga + be;
        v1.y = ((float)hbuf[i][5] - mean) * ga + be;
        v1.z = ((float)hbuf[i][6] - mean) * ga + be;
        v1.w = ((float)hbuf[i][7] - mean) * ga + be;
        orow[e4] = v0;
        orow[e4 + 1] = v1;
    }
}

extern "C" void kernel_launch(void* const* d_in, const int* in_sizes, int n_in,
                              void* d_out, int out_size, void* d_ws, size_t ws_size,
                              hipStream_t stream) {
    const float* x     = (const float*)d_in[0];
    const float* wqkv  = (const float*)d_in[1];
    const float* wout  = (const float*)d_in[2];
    const float* b_out = (const float*)d_in[3];
    const float* gamma = (const float*)d_in[4];
    const float* beta  = (const float*)d_in[5];
    if (ws_size < WS_NEED) return;
    char* ws = (char*)d_ws;
    _Float16* Wb = (_Float16*)(ws + WS_WQKV);
    _Float16* Wo = (_Float16*)(ws + WS_WOUT);
    float* S  = (float*)(ws + WS_S);
    float* Z  = (float*)(ws + WS_Z);
    float* St = (float*)(ws + WS_ST);

    k0_prep<<<389, 256, 0, stream>>>(wqkv, wout, ws);
    k1_kv<<<dim3(64, 8), 256, 0, stream>>>(x, Wb, S, Z);
    k3_main<<<dim3(512, 8), 256, 0, stream>>>(x, Wb, Wo, S, Z, b_out, (char*)d_out, St);
    k4_norm<<<dim3(128, 8), 256, 0, stream>>>((float*)d_out, St, gamma, beta);
}

// Round 4
// 205.050 us; speedup vs baseline: 1.5611x; 1.1234x over previous
//
#include <hip/hip_runtime.h>

#define BATCH 8
#define DIMC 128
#define NTOT 32768
#define HEADS 4
#define DHEAD 32
#define SCALE_Q 0.17677669529663687f

typedef _Float16 half8  __attribute__((ext_vector_type(8)));
typedef _Float16 half4v __attribute__((ext_vector_type(4)));
typedef _Float16 half2v __attribute__((ext_vector_type(2)));
typedef float    f32x4  __attribute__((ext_vector_type(4)));

// workspace byte offsets (all 16B aligned)
#define WS_WQKV 0        // _Float16[384*128]   = 98304 B
#define WS_WOUT 98304    // _Float16[128*128]   = 32768 B
#define WS_S    131072   // float[8*4*32*32]    = 131072 B
#define WS_Z    262144   // float[8*4*32]       = 4096 B
#define WS_ST   266240   // float[16]           (64 B)
#define WS_CT   266304   // _Float16[8*4*32*32] = 65536 B  (c^T, [b][h][e][d])
#define WS_NEED 331840

// ---------------- K0: convert weights to f16, zero accumulators ----------------
__global__ void k0_prep(const float* __restrict__ wqkv, const float* __restrict__ wout,
                        char* __restrict__ ws) {
    int i = blockIdx.x * 256 + threadIdx.x;
    _Float16* Wb = (_Float16*)(ws + WS_WQKV);
    _Float16* Wo = (_Float16*)(ws + WS_WOUT);
    float* S  = (float*)(ws + WS_S);
    float* Z  = (float*)(ws + WS_Z);
    float* St = (float*)(ws + WS_ST);
    if (i < 49152) Wb[i] = (_Float16)wqkv[i];
    int j = i - 49152;
    if (j >= 0 && j < 16384) Wo[j] = (_Float16)wout[j];
    int k = j - 16384;
    if (k >= 0 && k < 32768) S[k] = 0.f;
    int m = k - 32768;
    if (m >= 0 && m < 1024) Z[m] = 0.f;
    int s = m - 1024;
    if (s >= 0 && s < 16) St[s] = 0.f;
}

// ---------------- K1: k,v projection + S = sum_n exp(k) v^T, Z = sum_n exp(k) ----------------
// (256,2): higher min-wave bounds forced VGPR caps + scratch spills (round 2). LDS 49 KB -> 3 blocks/CU.
__global__ __launch_bounds__(256, 2) void k1_kv(const float* __restrict__ x,
                                                const _Float16* __restrict__ Wb,
                                                float* __restrict__ S,
                                                float* __restrict__ Z) {
    __shared__ _Float16 Xb[64][136];   // x^T tile: [j][c swizzled]
    __shared__ _Float16 KB[128][64];   // exp(k): [h*32+d][j swizzled]  (stride 128B, swizzle-protected)
    __shared__ _Float16 VB[128][64];   // v:      [h*32+e][j swizzled]
    const int t = threadIdx.x;
    const int lane = t & 63, w = t >> 6, g = lane >> 4, l15 = lane & 15;
    const int b = blockIdx.y;

    half8 af[4][4];
#pragma unroll
    for (int mt = 0; mt < 4; ++mt)
#pragma unroll
        for (int kc = 0; kc < 4; ++kc)
            af[mt][kc] = *(const half8*)(Wb + (size_t)(128 + (w * 4 + mt) * 16 + l15) * 128 + kc * 32 + 8 * g);

    f32x4 sacc[2][2];
#pragma unroll
    for (int dm = 0; dm < 2; ++dm)
#pragma unroll
        for (int en = 0; en < 2; ++en) sacc[dm][en] = (f32x4){0.f, 0.f, 0.f, 0.f};
    float zpart = 0.f;

    const int j4 = t & 15, c0 = t >> 4;
    const int sxw = (j4 & 7) << 3;  // staging swizzle for rows 4*j4+r (r<4)

    for (int it = 0; it < 8; ++it) {
        const int j0 = (blockIdx.x + 64 * it) * 64;
        __syncthreads();
#pragma unroll
        for (int cc = 0; cc < 8; ++cc) {
            const int c = c0 + 16 * cc;
            const float4 v4 = *(const float4*)(x + ((size_t)b * DIMC + c) * NTOT + j0 + 4 * j4);
            Xb[4 * j4 + 0][c ^ sxw] = (_Float16)v4.x;
            Xb[4 * j4 + 1][c ^ sxw] = (_Float16)v4.y;
            Xb[4 * j4 + 2][c ^ sxw] = (_Float16)v4.z;
            Xb[4 * j4 + 3][c ^ sxw] = (_Float16)v4.w;
        }
        __syncthreads();
        half8 bf[4][4];
#pragma unroll
        for (int nt = 0; nt < 4; ++nt) {
            const int sb = ((4 * nt + (l15 >> 2)) & 7) << 3;
#pragma unroll
            for (int kc = 0; kc < 4; ++kc)
                bf[nt][kc] = *(const half8*)(&Xb[nt * 16 + l15][(kc * 32 + 8 * g) ^ sb]);
        }
#pragma unroll
        for (int mt = 0; mt < 4; ++mt) {
            f32x4 a0 = (f32x4){0.f,0.f,0.f,0.f}, a1 = a0, a2 = a0, a3 = a0;
#pragma unroll
            for (int kc = 0; kc < 4; ++kc) {
                a0 = __builtin_amdgcn_mfma_f32_16x16x32_f16(af[mt][kc], bf[0][kc], a0, 0, 0, 0);
                a1 = __builtin_amdgcn_mfma_f32_16x16x32_f16(af[mt][kc], bf[1][kc], a1, 0, 0, 0);
                a2 = __builtin_amdgcn_mfma_f32_16x16x32_f16(af[mt][kc], bf[2][kc], a2, 0, 0, 0);
                a3 = __builtin_amdgcn_mfma_f32_16x16x32_f16(af[mt][kc], bf[3][kc], a3, 0, 0, 0);
            }
            const int lr0 = (w * 4 + mt) * 16 + g * 4;
            const int skv = (((w * 4 + mt) * 4 + g) & 7) << 3;  // ((lr0+r)>>2)&7, r<4
#pragma unroll
            for (int nt = 0; nt < 4; ++nt) {
                const f32x4 a = (nt == 0) ? a0 : (nt == 1) ? a1 : (nt == 2) ? a2 : a3;
                const int jn = (nt * 16 + l15) ^ skv;
                if (lr0 < 128) {
#pragma unroll
                    for (int r = 0; r < 4; ++r) KB[lr0 + r][jn] = (_Float16)__expf(a[r]);
                } else {
#pragma unroll
                    for (int r = 0; r < 4; ++r) VB[lr0 - 128 + r][jn] = (_Float16)a[r];
                }
            }
        }
        __syncthreads();
#pragma unroll
        for (int dm = 0; dm < 2; ++dm) {
            const int sr = ((4 * dm + (l15 >> 2)) & 7) << 3;
#pragma unroll
            for (int en = 0; en < 2; ++en)
#pragma unroll
                for (int kc = 0; kc < 2; ++kc) {
                    half8 ka = *(const half8*)(&KB[w * 32 + dm * 16 + l15][(kc * 32 + 8 * g) ^ sr]);
                    half8 vb = *(const half8*)(&VB[w * 32 + en * 16 + l15][(kc * 32 + 8 * g) ^ sr]);
                    sacc[dm][en] = __builtin_amdgcn_mfma_f32_16x16x32_f16(ka, vb, sacc[dm][en], 0, 0, 0);
                }
        }
        {
            const int zr = lane >> 1;
            const int sz = ((zr >> 2) & 7) << 3;
#pragma unroll
            for (int s8 = 0; s8 < 4; ++s8) {
                half8 hv = *(const half8*)(&KB[w * 32 + zr][((lane & 1) * 32 + 8 * s8) ^ sz]);
#pragma unroll
                for (int e = 0; e < 8; ++e) zpart += (float)hv[e];
            }
        }
    }
    {
        float zt = zpart + __shfl_xor(zpart, 1);
        if ((lane & 1) == 0) atomicAdd(&Z[(b * HEADS + w) * DHEAD + (lane >> 1)], zt);
    }
#pragma unroll
    for (int dm = 0; dm < 2; ++dm)
#pragma unroll
        for (int en = 0; en < 2; ++en)
#pragma unroll
            for (int r = 0; r < 4; ++r)
                atomicAdd(&S[((size_t)(b * HEADS + w) * DHEAD + dm * 16 + g * 4 + r) * DHEAD + en * 16 + l15],
                          sacc[dm][en][r]);
}

// ---------------- K2: CT[b][h][e][d] = S[b][h][d][e] / Z[b][h][d]  (f16) ----------------
__global__ void k2_ct(const float* __restrict__ S, const float* __restrict__ Z,
                      _Float16* __restrict__ CT) {
    int i = blockIdx.x * 256 + threadIdx.x;  // 32768
    int d = i & 31, e = (i >> 5) & 31, bh = i >> 10;
    CT[i] = (_Float16)(S[(bh * 32 + d) * 32 + e] / Z[bh * 32 + d]);
}

// ---------------- K3: q proj + d-softmax + out = cT@E (MFMA) + y (f16 stash) + stats ----------------
__global__ __launch_bounds__(256, 2) void k3_main(const float* __restrict__ x,
                                                  const _Float16* __restrict__ Wb,
                                                  const _Float16* __restrict__ Wo,
                                                  const _Float16* __restrict__ CT,
                                                  const float* __restrict__ b_out,
                                                  char* __restrict__ ybase,
                                                  float* __restrict__ St) {
    __shared__ _Float16 Xb[64][136];  // phase 1-2: x^T; phase 3-4: reused as oT [j][c]
    __shared__ _Float16 qT[64][136];  // E = exp(q): [j][d]
    __shared__ float scl[4][64];      // SCALE/colsum per [head][j]
    __shared__ float red[8];
    const int t = threadIdx.x;
    const int lane = t & 63, w = t >> 6, g = lane >> 4, l15 = lane & 15;
    const int b = blockIdx.y;
    const int j0 = blockIdx.x * 64;

    // phase 1: stage x^T tile (swizzled)
    {
        const int j4 = t & 15, c0 = t >> 4;
        const int sxw = (j4 & 7) << 3;
#pragma unroll
        for (int cc = 0; cc < 8; ++cc) {
            const int c = c0 + 16 * cc;
            const float4 v4 = *(const float4*)(x + ((size_t)b * DIMC + c) * NTOT + j0 + 4 * j4);
            Xb[4 * j4 + 0][c ^ sxw] = (_Float16)v4.x;
            Xb[4 * j4 + 1][c ^ sxw] = (_Float16)v4.y;
            Xb[4 * j4 + 2][c ^ sxw] = (_Float16)v4.z;
            Xb[4 * j4 + 3][c ^ sxw] = (_Float16)v4.w;
        }
    }
    __syncthreads();
    // phase 2: q GEMM (rows 0..127 = head w for wave w); store E=exp(q) f16, colsum -> scl
    {
        half8 bf[4][4];
#pragma unroll
        for (int nt = 0; nt < 4; ++nt) {
            const int sb = ((4 * nt + (l15 >> 2)) & 7) << 3;
#pragma unroll
            for (int kc = 0; kc < 4; ++kc)
                bf[nt][kc] = *(const half8*)(&Xb[nt * 16 + l15][(kc * 32 + 8 * g) ^ sb]);
        }
        float ps[4] = {0.f, 0.f, 0.f, 0.f};
#pragma unroll
        for (int mi = 0; mi < 2; ++mi) {
            const int mt = w * 2 + mi;
            half8 af[4];
#pragma unroll
            for (int kc = 0; kc < 4; ++kc)
                af[kc] = *(const half8*)(Wb + (size_t)(mt * 16 + l15) * 128 + kc * 32 + 8 * g);
            f32x4 acc[4];
#pragma unroll
            for (int nt = 0; nt < 4; ++nt) acc[nt] = (f32x4){0.f, 0.f, 0.f, 0.f};
#pragma unroll
            for (int kc = 0; kc < 4; ++kc)
#pragma unroll
                for (int nt = 0; nt < 4; ++nt)
                    acc[nt] = __builtin_amdgcn_mfma_f32_16x16x32_f16(af[kc], bf[nt][kc], acc[nt], 0, 0, 0);
#pragma unroll
            for (int nt = 0; nt < 4; ++nt) {
                const int sb = ((4 * nt + (l15 >> 2)) & 7) << 3;
                half4v p;
#pragma unroll
                for (int r = 0; r < 4; ++r) {
                    const float e = __expf(acc[nt][r]);
                    ps[nt] += e;
                    p[r] = (_Float16)e;
                }
                *(half4v*)(&qT[nt * 16 + l15][(mt * 16 + g * 4) ^ sb]) = p;
            }
        }
        // reduce colsum across g (lanes l15, l15+16, l15+32, l15+48 hold head-w partials)
#pragma unroll
        for (int nt = 0; nt < 4; ++nt) {
            ps[nt] += __shfl_xor(ps[nt], 16);
            ps[nt] += __shfl_xor(ps[nt], 32);
        }
        if (lane < 16) {
#pragma unroll
            for (int nt = 0; nt < 4; ++nt) scl[w][nt * 16 + lane] = SCALE_Q / ps[nt];
        }
    }
    __syncthreads();
    // phase 3: out(c,j) = scl[j] * sum_d cT(e,d) E(d,j), via 8 MFMAs; write oT (aliases Xb)
    {
        half8 ca[2];
#pragma unroll
        for (int et = 0; et < 2; ++et)
            ca[et] = *(const half8*)(CT + ((size_t)(b * HEADS + w) * DHEAD + et * 16 + l15) * DHEAD + 8 * g);
        half8 bf3[4];
        float sc[4];
#pragma unroll
        for (int nt = 0; nt < 4; ++nt) {
            const int sb = ((4 * nt + (l15 >> 2)) & 7) << 3;
            bf3[nt] = *(const half8*)(&qT[nt * 16 + l15][(w * 32 + 8 * g) ^ sb]);
            sc[nt] = scl[w][nt * 16 + l15];
        }
#pragma unroll
        for (int et = 0; et < 2; ++et) {
            f32x4 acc[4];
#pragma unroll
            for (int nt = 0; nt < 4; ++nt) acc[nt] = (f32x4){0.f, 0.f, 0.f, 0.f};
#pragma unroll
            for (int nt = 0; nt < 4; ++nt)
                acc[nt] = __builtin_amdgcn_mfma_f32_16x16x32_f16(ca[et], bf3[nt], acc[nt], 0, 0, 0);
#pragma unroll
            for (int nt = 0; nt < 4; ++nt) {
                const int sb = ((4 * nt + (l15 >> 2)) & 7) << 3;
                half4v p;
#pragma unroll
                for (int r = 0; r < 4; ++r) p[r] = (_Float16)(acc[nt][r] * sc[nt]);
                *(half4v*)(&Xb[nt * 16 + l15][(w * 32 + et * 16 + g * 4) ^ sb]) = p;
            }
        }
    }
    __syncthreads();
    // phase 4: y = Wout @ out + b_out -> f16 stash in d_out rows, + stats
    float ssum = 0.f, ssq = 0.f;
    {
        half8 bf[4][4];
#pragma unroll
        for (int nt = 0; nt < 4; ++nt) {
            const int sb = ((4 * nt + (l15 >> 2)) & 7) << 3;
#pragma unroll
            for (int kc = 0; kc < 4; ++kc)
                bf[nt][kc] = *(const half8*)(&Xb[nt * 16 + l15][(kc * 32 + 8 * g) ^ sb]);
        }
#pragma unroll
        for (int mi = 0; mi < 2; ++mi) {
            const int mt = w * 2 + mi;
            const int o0 = mt * 16 + g * 4;
            half8 af[4];
#pragma unroll
            for (int kc = 0; kc < 4; ++kc)
                af[kc] = *(const half8*)(Wo + (size_t)(mt * 16 + l15) * 128 + kc * 32 + 8 * g);
            f32x4 acc[4];
#pragma unroll
            for (int nt = 0; nt < 4; ++nt) acc[nt] = (f32x4){0.f, 0.f, 0.f, 0.f};
#pragma unroll
            for (int kc = 0; kc < 4; ++kc)
#pragma unroll
                for (int nt = 0; nt < 4; ++nt)
                    acc[nt] = __builtin_amdgcn_mfma_f32_16x16x32_f16(af[kc], bf[nt][kc], acc[nt], 0, 0, 0);
            float bo[4];
#pragma unroll
            for (int r = 0; r < 4; ++r) bo[r] = b_out[o0 + r];
#pragma unroll
            for (int r = 0; r < 4; ++r) {
                _Float16* yrow = (_Float16*)(ybase + (size_t)(b * DIMC + o0 + r) * 131072 + 65536);
#pragma unroll
                for (int nt = 0; nt < 4; ++nt) {
                    const int jn = j0 + nt * 16 + l15;
                    const float yv = acc[nt][r] + bo[r];
                    ssum += yv;
                    ssq += yv * yv;
                    yrow[jn] = (_Float16)yv;
                }
            }
        }
    }
#pragma unroll
    for (int m = 32; m; m >>= 1) { ssum += __shfl_xor(ssum, m); ssq += __shfl_xor(ssq, m); }
    if (lane == 0) { red[w] = ssum; red[4 + w] = ssq; }
    __syncthreads();
    if (t == 0) {
        atomicAdd(&St[b * 2 + 0], red[0] + red[1] + red[2] + red[3]);
        atomicAdd(&St[b * 2 + 1], red[4] + red[5] + red[6] + red[7]);
    }
}

// ---------------- K4: layernorm; read f16 stash (2nd half of own row), write f32 ----------------
__global__ __launch_bounds__(256) void k4_norm(float* __restrict__ out, const float* __restrict__ St,
                                               const float* __restrict__ gamma,
                                               const float* __restrict__ beta) {
    const int o = blockIdx.x;
    const int b = blockIdx.y;
    const int t = threadIdx.x;
    const size_t row = (size_t)b * DIMC + o;
    const float n = (float)DIMC * (float)NTOT;
    const float mean = St[b * 2] / n;
    const float var = St[b * 2 + 1] / n - mean * mean;
    const float rs = rsqrtf(var + 1e-5f);
    const float ga = gamma[o] * rs;
    const float be = beta[o];
    const half8* yh = (const half8*)((const char*)out + row * 131072 + 65536);
    half8 hbuf[16];
#pragma unroll
    for (int i = 0; i < 16; ++i) hbuf[i] = yh[i * 256 + t];
    __syncthreads();  // all reads before any f32 overwrite (stash lives in this row)
    float4* orow = (float4*)(out + row * NTOT);
#pragma unroll
    for (int i = 0; i < 16; ++i) {
        const int e4 = (i * 256 + t) * 2;
        float4 v0, v1;
        v0.x = ((float)hbuf[i][0] - mean) * ga + be;
        v0.y = ((float)hbuf[i][1] - mean) * ga + be;
        v0.z = ((float)hbuf[i][2] - mean) * ga + be;
        v0.w = ((float)hbuf[i][3] - mean) * ga + be;
        v1.x = ((float)hbuf[i][4] - mean) * ga + be;
        v1.y = ((float)hbuf[i][5] - mean) * ga + be;
        v1.z = ((float)hbuf[i][6] - mean) * ga + be;
        v1.w = ((float)hbuf[i][7] - mean) * ga + be;
        orow[e4] = v0;
        orow[e4 + 1] = v1;
    }
}

extern "C" void kernel_launch(void* const* d_in, const int* in_sizes, int n_in,
                              void* d_out, int out_size, void* d_ws, size_t ws_size,
                              hipStream_t stream) {
    const float* x     = (const float*)d_in[0];
    const float* wqkv  = (const float*)d_in[1];
    const float* wout  = (const float*)d_in[2];
    const float* b_out = (const float*)d_in[3];
    const float* gamma = (const float*)d_in[4];
    const float* beta  = (const float*)d_in[5];
    if (ws_size < WS_NEED) return;
    char* ws = (char*)d_ws;
    _Float16* Wb = (_Float16*)(ws + WS_WQKV);
    _Float16* Wo = (_Float16*)(ws + WS_WOUT);
    float* S  = (float*)(ws + WS_S);
    float* Z  = (float*)(ws + WS_Z);
    float* St = (float*)(ws + WS_ST);
    _Float16* CT = (_Float16*)(ws + WS_CT);

    k0_prep<<<389, 256, 0, stream>>>(wqkv, wout, ws);
    k1_kv<<<dim3(64, 8), 256, 0, stream>>>(x, Wb, S, Z);
    k2_ct<<<128, 256, 0, stream>>>(S, Z, CT);
    k3_main<<<dim3(512, 8), 256, 0, stream>>>(x, Wb, Wo, CT, b_out, (char*)d_out, St);
    k4_norm<<<dim3(128, 8), 256, 0, stream>>>((float*)d_out, St, gamma, beta);
}

// Round 5
// 139.270 us; speedup vs baseline: 2.2984x; 1.4723x over previous
//
#include <hip/hip_runtime.h>

#define BATCH 8
#define DIMC 128
#define NTOT 32768
#define HEADS 4
#define DHEAD 32
#define SCALE_Q 0.17677669529663687f

typedef _Float16 half8  __attribute__((ext_vector_type(8)));
typedef _Float16 half4v __attribute__((ext_vector_type(4)));
typedef _Float16 half2v __attribute__((ext_vector_type(2)));
typedef float    f32x4  __attribute__((ext_vector_type(4)));

// workspace byte offsets (all 16B aligned)
#define WS_WQKV 0        // _Float16[384*128]   = 98304 B
#define WS_WOUT 98304    // _Float16[128*128]   = 32768 B
#define WS_S    131072   // float[8*4*32*32]    = 131072 B
#define WS_Z    262144   // float[8*4*32]       = 4096 B
#define WS_ST   266240   // float[16]           (64 B)
#define WS_CT   266304   // _Float16[8*4*32*32] = 65536 B  (c^T, [b][h][e][d])
#define WS_NEED 331840

// ---------------- K0: convert weights to f16, zero accumulators ----------------
__global__ void k0_prep(const float* __restrict__ wqkv, const float* __restrict__ wout,
                        char* __restrict__ ws) {
    int i = blockIdx.x * 256 + threadIdx.x;
    _Float16* Wb = (_Float16*)(ws + WS_WQKV);
    _Float16* Wo = (_Float16*)(ws + WS_WOUT);
    float* S  = (float*)(ws + WS_S);
    float* Z  = (float*)(ws + WS_Z);
    float* St = (float*)(ws + WS_ST);
    if (i < 49152) Wb[i] = (_Float16)wqkv[i];
    int j = i - 49152;
    if (j >= 0 && j < 16384) Wo[j] = (_Float16)wout[j];
    int k = j - 16384;
    if (k >= 0 && k < 32768) S[k] = 0.f;
    int m = k - 32768;
    if (m >= 0 && m < 1024) Z[m] = 0.f;
    int s = m - 1024;
    if (s >= 0 && s < 16) St[s] = 0.f;
}

// ---------------- K1: k,v projection + S = sum_n exp(k) v^T, Z = sum_n exp(k) ----------------
// Pipelined: tile t+1 global loads issued before tile-t compute; Xb writes overlap S-phase.
// (256,2): higher min-wave bounds forced VGPR caps + scratch spills (round 2).
__global__ __launch_bounds__(256, 2) void k1_kv(const float* __restrict__ x,
                                                const _Float16* __restrict__ Wb,
                                                float* __restrict__ S,
                                                float* __restrict__ Z) {
    __shared__ _Float16 Xb[64][136];   // x^T tile: [j][c swizzled]
    __shared__ _Float16 KB[128][64];   // exp(k): [h*32+d][j swizzled]
    __shared__ _Float16 VB[128][64];   // v:      [h*32+e][j swizzled]
    const int t = threadIdx.x;
    const int lane = t & 63, w = t >> 6, g = lane >> 4, l15 = lane & 15;
    const int b = blockIdx.y;

    half8 af[4][4];
#pragma unroll
    for (int mt = 0; mt < 4; ++mt)
#pragma unroll
        for (int kc = 0; kc < 4; ++kc)
            af[mt][kc] = *(const half8*)(Wb + (size_t)(128 + (w * 4 + mt) * 16 + l15) * 128 + kc * 32 + 8 * g);

    f32x4 sacc[2][2];
#pragma unroll
    for (int dm = 0; dm < 2; ++dm)
#pragma unroll
        for (int en = 0; en < 2; ++en) sacc[dm][en] = (f32x4){0.f, 0.f, 0.f, 0.f};
    float zpart = 0.f;

    const int j4 = t & 15, c0 = t >> 4;
    const int sxw = (j4 & 7) << 3;

    // prologue: load + stage tile 0
    float4 xr[8];
#pragma unroll
    for (int cc = 0; cc < 8; ++cc)
        xr[cc] = *(const float4*)(x + ((size_t)b * DIMC + c0 + 16 * cc) * NTOT + blockIdx.x * 64 + 4 * j4);
#pragma unroll
    for (int cc = 0; cc < 8; ++cc) {
        const int c = c0 + 16 * cc;
        Xb[4 * j4 + 0][c ^ sxw] = (_Float16)xr[cc].x;
        Xb[4 * j4 + 1][c ^ sxw] = (_Float16)xr[cc].y;
        Xb[4 * j4 + 2][c ^ sxw] = (_Float16)xr[cc].z;
        Xb[4 * j4 + 3][c ^ sxw] = (_Float16)xr[cc].w;
    }

    for (int it = 0; it < 8; ++it) {
        if (it < 7) {
            const int j0n = (blockIdx.x + 64 * (it + 1)) * 64;
#pragma unroll
            for (int cc = 0; cc < 8; ++cc)
                xr[cc] = *(const float4*)(x + ((size_t)b * DIMC + c0 + 16 * cc) * NTOT + j0n + 4 * j4);
        }
        __syncthreads();   // Xb(tile it) visible; prev-iter KB/VB reads done
        half8 bf[4][4];
#pragma unroll
        for (int nt = 0; nt < 4; ++nt) {
            const int sb = ((4 * nt + (l15 >> 2)) & 7) << 3;
#pragma unroll
            for (int kc = 0; kc < 4; ++kc)
                bf[nt][kc] = *(const half8*)(&Xb[nt * 16 + l15][(kc * 32 + 8 * g) ^ sb]);
        }
#pragma unroll
        for (int mt = 0; mt < 4; ++mt) {
            f32x4 a0 = (f32x4){0.f,0.f,0.f,0.f}, a1 = a0, a2 = a0, a3 = a0;
#pragma unroll
            for (int kc = 0; kc < 4; ++kc) {
                a0 = __builtin_amdgcn_mfma_f32_16x16x32_f16(af[mt][kc], bf[0][kc], a0, 0, 0, 0);
                a1 = __builtin_amdgcn_mfma_f32_16x16x32_f16(af[mt][kc], bf[1][kc], a1, 0, 0, 0);
                a2 = __builtin_amdgcn_mfma_f32_16x16x32_f16(af[mt][kc], bf[2][kc], a2, 0, 0, 0);
                a3 = __builtin_amdgcn_mfma_f32_16x16x32_f16(af[mt][kc], bf[3][kc], a3, 0, 0, 0);
            }
            const int lr0 = (w * 4 + mt) * 16 + g * 4;
            const int skv = (((w * 4 + mt) * 4 + g) & 7) << 3;
#pragma unroll
            for (int nt = 0; nt < 4; ++nt) {
                const f32x4 a = (nt == 0) ? a0 : (nt == 1) ? a1 : (nt == 2) ? a2 : a3;
                const int jn = (nt * 16 + l15) ^ skv;
                if (lr0 < 128) {
#pragma unroll
                    for (int r = 0; r < 4; ++r) KB[lr0 + r][jn] = (_Float16)__expf(a[r]);
                } else {
#pragma unroll
                    for (int r = 0; r < 4; ++r) VB[lr0 - 128 + r][jn] = (_Float16)a[r];
                }
            }
        }
        __syncthreads();   // KB/VB ready; Xb reads done
        // stage tile it+1 into Xb, overlapping the S/Z phase
        if (it < 7) {
#pragma unroll
            for (int cc = 0; cc < 8; ++cc) {
                const int c = c0 + 16 * cc;
                Xb[4 * j4 + 0][c ^ sxw] = (_Float16)xr[cc].x;
                Xb[4 * j4 + 1][c ^ sxw] = (_Float16)xr[cc].y;
                Xb[4 * j4 + 2][c ^ sxw] = (_Float16)xr[cc].z;
                Xb[4 * j4 + 3][c ^ sxw] = (_Float16)xr[cc].w;
            }
        }
#pragma unroll
        for (int dm = 0; dm < 2; ++dm) {
            const int sr = ((4 * dm + (l15 >> 2)) & 7) << 3;
#pragma unroll
            for (int en = 0; en < 2; ++en)
#pragma unroll
                for (int kc = 0; kc < 2; ++kc) {
                    half8 ka = *(const half8*)(&KB[w * 32 + dm * 16 + l15][(kc * 32 + 8 * g) ^ sr]);
                    half8 vb = *(const half8*)(&VB[w * 32 + en * 16 + l15][(kc * 32 + 8 * g) ^ sr]);
                    sacc[dm][en] = __builtin_amdgcn_mfma_f32_16x16x32_f16(ka, vb, sacc[dm][en], 0, 0, 0);
                }
        }
        {
            const int zr = lane >> 1;
            const int sz = ((zr >> 2) & 7) << 3;
#pragma unroll
            for (int s8 = 0; s8 < 4; ++s8) {
                half8 hv = *(const half8*)(&KB[w * 32 + zr][((lane & 1) * 32 + 8 * s8) ^ sz]);
#pragma unroll
                for (int e = 0; e < 8; ++e) zpart += (float)hv[e];
            }
        }
    }
    {
        float zt = zpart + __shfl_xor(zpart, 1);
        if ((lane & 1) == 0) atomicAdd(&Z[(b * HEADS + w) * DHEAD + (lane >> 1)], zt);
    }
#pragma unroll
    for (int dm = 0; dm < 2; ++dm)
#pragma unroll
        for (int en = 0; en < 2; ++en)
#pragma unroll
            for (int r = 0; r < 4; ++r)
                atomicAdd(&S[((size_t)(b * HEADS + w) * DHEAD + dm * 16 + g * 4 + r) * DHEAD + en * 16 + l15],
                          sacc[dm][en][r]);
}

// ---------------- K2: CT[b][h][e][d] = S[b][h][d][e] / Z[b][h][d]  (f16) ----------------
__global__ void k2_ct(const float* __restrict__ S, const float* __restrict__ Z,
                      _Float16* __restrict__ CT) {
    int i = blockIdx.x * 256 + threadIdx.x;  // 32768
    int d = i & 31, e = (i >> 5) & 31, bh = i >> 10;
    CT[i] = (_Float16)(S[(bh * 32 + d) * 32 + e] / Z[bh * 32 + d]);
}

// ---------------- K3: pipelined q proj + d-softmax + out = cT@E + y (f16 stash) + stats ----------------
// grid (64,8), 8 j-tiles per block; 2 barriers/iter; next-tile loads hidden under compute.
__global__ __launch_bounds__(256, 2) void k3_main(const float* __restrict__ x,
                                                  const _Float16* __restrict__ Wb,
                                                  const _Float16* __restrict__ Wo,
                                                  const _Float16* __restrict__ CT,
                                                  const float* __restrict__ b_out,
                                                  char* __restrict__ ybase,
                                                  float* __restrict__ St) {
    __shared__ _Float16 Xb[64][136];  // x^T tile
    __shared__ _Float16 qT[64][136];  // E = exp(q): [j][d]
    __shared__ _Float16 oT[64][136];  // out^T: [j][c]
    __shared__ float scl[4][64];      // SCALE/colsum per [head][j]
    __shared__ float red[8];
    const int t = threadIdx.x;
    const int lane = t & 63, w = t >> 6, g = lane >> 4, l15 = lane & 15;
    const int b = blockIdx.y;
    const int j4 = t & 15, c0 = t >> 4;
    const int sxw = (j4 & 7) << 3;

    // loop-invariant register fragments
    half8 wa[2][4];  // Wb rows (w*2+mi)*16.. (q projection A-frags)
#pragma unroll
    for (int mi = 0; mi < 2; ++mi)
#pragma unroll
        for (int kc = 0; kc < 4; ++kc)
            wa[mi][kc] = *(const half8*)(Wb + (size_t)((w * 2 + mi) * 16 + l15) * 128 + kc * 32 + 8 * g);
    half8 ca[2];
#pragma unroll
    for (int et = 0; et < 2; ++et)
        ca[et] = *(const half8*)(CT + ((size_t)(b * HEADS + w) * DHEAD + et * 16 + l15) * DHEAD + 8 * g);

    float ssum = 0.f, ssq = 0.f;

    // prologue: load + stage tile 0
    float4 xr[8];
#pragma unroll
    for (int cc = 0; cc < 8; ++cc)
        xr[cc] = *(const float4*)(x + ((size_t)b * DIMC + c0 + 16 * cc) * NTOT + blockIdx.x * 64 + 4 * j4);
#pragma unroll
    for (int cc = 0; cc < 8; ++cc) {
        const int c = c0 + 16 * cc;
        Xb[4 * j4 + 0][c ^ sxw] = (_Float16)xr[cc].x;
        Xb[4 * j4 + 1][c ^ sxw] = (_Float16)xr[cc].y;
        Xb[4 * j4 + 2][c ^ sxw] = (_Float16)xr[cc].z;
        Xb[4 * j4 + 3][c ^ sxw] = (_Float16)xr[cc].w;
    }
    __syncthreads();

    for (int it = 0; it < 8; ++it) {
        const int j0 = (blockIdx.x + 64 * it) * 64;
        if (it < 7) {
            const int j0n = (blockIdx.x + 64 * (it + 1)) * 64;
#pragma unroll
            for (int cc = 0; cc < 8; ++cc)
                xr[cc] = *(const float4*)(x + ((size_t)b * DIMC + c0 + 16 * cc) * NTOT + j0n + 4 * j4);
        }
        // phase 2: q GEMM from Xb -> qT (E=exp), colsum -> scl
        {
            half8 bf[4][4];
#pragma unroll
            for (int nt = 0; nt < 4; ++nt) {
                const int sb = ((4 * nt + (l15 >> 2)) & 7) << 3;
#pragma unroll
                for (int kc = 0; kc < 4; ++kc)
                    bf[nt][kc] = *(const half8*)(&Xb[nt * 16 + l15][(kc * 32 + 8 * g) ^ sb]);
            }
            float ps[4] = {0.f, 0.f, 0.f, 0.f};
#pragma unroll
            for (int mi = 0; mi < 2; ++mi) {
                const int mt = w * 2 + mi;
                f32x4 acc[4];
#pragma unroll
                for (int nt = 0; nt < 4; ++nt) acc[nt] = (f32x4){0.f, 0.f, 0.f, 0.f};
#pragma unroll
                for (int kc = 0; kc < 4; ++kc)
#pragma unroll
                    for (int nt = 0; nt < 4; ++nt)
                        acc[nt] = __builtin_amdgcn_mfma_f32_16x16x32_f16(wa[mi][kc], bf[nt][kc], acc[nt], 0, 0, 0);
#pragma unroll
                for (int nt = 0; nt < 4; ++nt) {
                    const int sb = ((4 * nt + (l15 >> 2)) & 7) << 3;
                    half4v p;
#pragma unroll
                    for (int r = 0; r < 4; ++r) {
                        const float e = __expf(acc[nt][r]);
                        ps[nt] += e;
                        p[r] = (_Float16)e;
                    }
                    *(half4v*)(&qT[nt * 16 + l15][(mt * 16 + g * 4) ^ sb]) = p;
                }
            }
#pragma unroll
            for (int nt = 0; nt < 4; ++nt) {
                ps[nt] += __shfl_xor(ps[nt], 16);
                ps[nt] += __shfl_xor(ps[nt], 32);
            }
            if (lane < 16) {
#pragma unroll
                for (int nt = 0; nt < 4; ++nt) scl[w][nt * 16 + lane] = SCALE_Q / ps[nt];
            }
        }
        __syncthreads();   // qT/scl ready; Xb reads done
        // stage tile it+1 into Xb (overlaps phase 3)
        if (it < 7) {
#pragma unroll
            for (int cc = 0; cc < 8; ++cc) {
                const int c = c0 + 16 * cc;
                Xb[4 * j4 + 0][c ^ sxw] = (_Float16)xr[cc].x;
                Xb[4 * j4 + 1][c ^ sxw] = (_Float16)xr[cc].y;
                Xb[4 * j4 + 2][c ^ sxw] = (_Float16)xr[cc].z;
                Xb[4 * j4 + 3][c ^ sxw] = (_Float16)xr[cc].w;
            }
        }
        // phase 3: out(c,j) = scl[j] * sum_d cT(e,d) E(d,j) -> oT
        {
            half8 bf3[4];
            float sc[4];
#pragma unroll
            for (int nt = 0; nt < 4; ++nt) {
                const int sb = ((4 * nt + (l15 >> 2)) & 7) << 3;
                bf3[nt] = *(const half8*)(&qT[nt * 16 + l15][(w * 32 + 8 * g) ^ sb]);
                sc[nt] = scl[w][nt * 16 + l15];
            }
#pragma unroll
            for (int et = 0; et < 2; ++et) {
                f32x4 acc[4];
#pragma unroll
                for (int nt = 0; nt < 4; ++nt) acc[nt] = (f32x4){0.f, 0.f, 0.f, 0.f};
#pragma unroll
                for (int nt = 0; nt < 4; ++nt)
                    acc[nt] = __builtin_amdgcn_mfma_f32_16x16x32_f16(ca[et], bf3[nt], acc[nt], 0, 0, 0);
#pragma unroll
                for (int nt = 0; nt < 4; ++nt) {
                    const int sb = ((4 * nt + (l15 >> 2)) & 7) << 3;
                    half4v p;
#pragma unroll
                    for (int r = 0; r < 4; ++r) p[r] = (_Float16)(acc[nt][r] * sc[nt]);
                    *(half4v*)(&oT[nt * 16 + l15][(w * 32 + et * 16 + g * 4) ^ sb]) = p;
                }
            }
        }
        __syncthreads();   // oT ready; Xb(next) staged; qT/scl reads done
        // phase 4: y = Wout @ out + b_out -> f16 stash, + stats (no trailing barrier:
        // next phase-2's qT writes are safe — qT last read above; Xb already restaged)
        {
            half8 bf[4][4];
#pragma unroll
            for (int nt = 0; nt < 4; ++nt) {
                const int sb = ((4 * nt + (l15 >> 2)) & 7) << 3;
#pragma unroll
                for (int kc = 0; kc < 4; ++kc)
                    bf[nt][kc] = *(const half8*)(&oT[nt * 16 + l15][(kc * 32 + 8 * g) ^ sb]);
            }
#pragma unroll
            for (int mi = 0; mi < 2; ++mi) {
                const int mt = w * 2 + mi;
                const int o0 = mt * 16 + g * 4;
                half8 af[4];
#pragma unroll
                for (int kc = 0; kc < 4; ++kc)
                    af[kc] = *(const half8*)(Wo + (size_t)(mt * 16 + l15) * 128 + kc * 32 + 8 * g);
                f32x4 acc[4];
#pragma unroll
                for (int nt = 0; nt < 4; ++nt) acc[nt] = (f32x4){0.f, 0.f, 0.f, 0.f};
#pragma unroll
                for (int kc = 0; kc < 4; ++kc)
#pragma unroll
                    for (int nt = 0; nt < 4; ++nt)
                        acc[nt] = __builtin_amdgcn_mfma_f32_16x16x32_f16(af[kc], bf[nt][kc], acc[nt], 0, 0, 0);
                float bo[4];
#pragma unroll
                for (int r = 0; r < 4; ++r) bo[r] = b_out[o0 + r];
#pragma unroll
                for (int r = 0; r < 4; ++r) {
                    _Float16* yrow = (_Float16*)(ybase + (size_t)(b * DIMC + o0 + r) * 131072 + 65536);
#pragma unroll
                    for (int nt = 0; nt < 4; ++nt) {
                        const int jn = j0 + nt * 16 + l15;
                        const float yv = acc[nt][r] + bo[r];
                        ssum += yv;
                        ssq += yv * yv;
                        yrow[jn] = (_Float16)yv;
                    }
                }
            }
        }
        __syncthreads();   // oT reads done before next iter's phase-3 writes
    }
#pragma unroll
    for (int m = 32; m; m >>= 1) { ssum += __shfl_xor(ssum, m); ssq += __shfl_xor(ssq, m); }
    if (lane == 0) { red[w] = ssum; red[4 + w] = ssq; }
    __syncthreads();
    if (t == 0) {
        atomicAdd(&St[b * 2 + 0], red[0] + red[1] + red[2] + red[3]);
        atomicAdd(&St[b * 2 + 1], red[4] + red[5] + red[6] + red[7]);
    }
}

// ---------------- K4: layernorm; read f16 stash (2nd half of own row), write f32 ----------------
__global__ __launch_bounds__(256) void k4_norm(float* __restrict__ out, const float* __restrict__ St,
                                               const float* __restrict__ gamma,
                                               const float* __restrict__ beta) {
    const int o = blockIdx.x;
    const int b = blockIdx.y;
    const int t = threadIdx.x;
    const size_t row = (size_t)b * DIMC + o;
    const float n = (float)DIMC * (float)NTOT;
    const float mean = St[b * 2] / n;
    const float var = St[b * 2 + 1] / n - mean * mean;
    const float rs = rsqrtf(var + 1e-5f);
    const float ga = gamma[o] * rs;
    const float be = beta[o];
    const half8* yh = (const half8*)((const char*)out + row * 131072 + 65536);
    half8 hbuf[16];
#pragma unroll
    for (int i = 0; i < 16; ++i) hbuf[i] = yh[i * 256 + t];
    __syncthreads();  // all reads before any f32 overwrite (stash lives in this row)
    float4* orow = (float4*)(out + row * NTOT);
#pragma unroll
    for (int i = 0; i < 16; ++i) {
        const int e4 = (i * 256 + t) * 2;
        float4 v0, v1;
        v0.x = ((float)hbuf[i][0] - mean) * ga + be;
        v0.y = ((float)hbuf[i][1] - mean) * ga + be;
        v0.z = ((float)hbuf[i][2] - mean) * ga + be;
        v0.w = ((float)hbuf[i][3] - mean) * ga + be;
        v1.x = ((float)hbuf[i][4] - mean) * ga + be;
        v1.y = ((float)hbuf[i][5] - mean) * ga + be;
        v1.z = ((float)hbuf[i][6] - mean) * ga + be;
        v1.w = ((float)hbuf[i][7] - mean) * ga + be;
        orow[e4] = v0;
        orow[e4 + 1] = v1;
    }
}

extern "C" void kernel_launch(void* const* d_in, const int* in_sizes, int n_in,
                              void* d_out, int out_size, void* d_ws, size_t ws_size,
                              hipStream_t stream) {
    const float* x     = (const float*)d_in[0];
    const float* wqkv  = (const float*)d_in[1];
    const float* wout  = (const float*)d_in[2];
    const float* b_out = (const float*)d_in[3];
    const float* gamma = (const float*)d_in[4];
    const float* beta  = (const float*)d_in[5];
    if (ws_size < WS_NEED) return;
    char* ws = (char*)d_ws;
    _Float16* Wb = (_Float16*)(ws + WS_WQKV);
    _Float16* Wo = (_Float16*)(ws + WS_WOUT);
    float* S  = (float*)(ws + WS_S);
    float* Z  = (float*)(ws + WS_Z);
    float* St = (float*)(ws + WS_ST);
    _Float16* CT = (_Float16*)(ws + WS_CT);

    k0_prep<<<389, 256, 0, stream>>>(wqkv, wout, ws);
    k1_kv<<<dim3(64, 8), 256, 0, stream>>>(x, Wb, S, Z);
    k2_ct<<<128, 256, 0, stream>>>(S, Z, CT);
    k3_main<<<dim3(64, 8), 256, 0, stream>>>(x, Wb, Wo, CT, b_out, (char*)d_out, St);
    k4_norm<<<dim3(128, 8), 256, 0, stream>>>((float*)d_out, St, gamma, beta);
}